// Round 7
// baseline (78.305 us; speedup 1.0000x reference)
//
#include <hip/hip_runtime.h>
#include <cmath>

// QuanvolutionSelfAttentionClassifier on MI355X — round 7.
//
// Algebra (verified by R1/R2/R5/R6 passes): softmax over length-1 axis == 1
// -> attn_weights == mean_embeds (rotation/entangle params dead). With
// l = c*196 + p, embedding index d = p & 3; for input pixel (r,cc):
// d = (2*((r>>1)&1) + (cc>>1)) & 3.
//   logits[j] = lin_b[j] + sum_d M[d] * (cst[d][j] + T[d][j])
//   M[d]    = a + sum_pix x[pix]*gm(pix),   a = sum_c conv_b[c]/4
//   T[d][j] = sum_{pix: d(pix)==d} x[pix] * G[pix][j]
//
// R7 = R6 byte-identical except the occupancy attribute. Diagnosis of the
// persistent ~85MB WRITE_SIZE across R1/R2/R5/R6: __launch_bounds__(256,2)
// sets only the waves-per-EU MINIMUM; the backend's default max (8/EU)
// lets the scheduler/RA target high occupancy, capping VGPRs at ~64 and
// demoting the float4 pipeline arrays to scratch (VGPR_Count 60-76 observed
// in every round regardless of structure; spill ~650B/thread drains through
// L3 to HBM each replay). Fix: pin amdgpu_waves_per_eu(2,2) -> 256-VGPR
// budget; live state ~110 VGPR fits with margin, no spill possible.

#define WS_A    9408
#define WS_CST  9409

__global__ void qsac_prep(const float* __restrict__ cw, const float* __restrict__ cb,
                          const float* __restrict__ lw, float* __restrict__ ws) {
  const int t = blockIdx.x * 98 + threadIdx.x;  // 8 x 98 = 784 pixels
  const int r = t / 28, cc = t - r * 28;
  const int kh = r & 1, kw = cc & 1;
  const int p = (r >> 1) * 14 + (cc >> 1);
  const float w0 = cw[(kh << 1) + kw],     w1 = cw[4 + (kh << 1) + kw],
              w2 = cw[8 + (kh << 1) + kw], w3 = cw[12 + (kh << 1) + kw];
  float g[10];
#pragma unroll
  for (int j = 0; j < 10; ++j)
    g[j] = w0 * lw[j * 784 + p]       + w1 * lw[j * 784 + 196 + p] +
           w2 * lw[j * 784 + 392 + p] + w3 * lw[j * 784 + 588 + p];
  const float gm = (w0 + w1 + w2 + w3) * (1.0f / 196.0f);
  // Layout: ws[ch*4704 + r*168 + cc*6 + k]; k<5 -> j=ch*5+k, k=5 -> 0|gm.
  const int pr = cc >> 1, e = cc & 1;
  float* d0 = ws + r * 168 + pr * 12 + e * 6;
  d0[0] = g[0]; d0[1] = g[1]; d0[2] = g[2]; d0[3] = g[3]; d0[4] = g[4]; d0[5] = 0.f;
  float* d1 = ws + 4704 + r * 168 + pr * 12 + e * 6;
  d1[0] = g[5]; d1[1] = g[6]; d1[2] = g[7]; d1[3] = g[8]; d1[4] = g[9]; d1[5] = gm;

  if (blockIdx.x == 0) {
    const int u = threadIdx.x;
    if (u < 40) {
      const int d = u / 10, j = u - (u / 10) * 10;
      const float b0 = cb[0], b1 = cb[1], b2 = cb[2], b3 = cb[3];
      float s = 0.f;
#pragma unroll 7
      for (int q = d; q < 196; q += 4)
        s += b0 * lw[j * 784 + q]       + b1 * lw[j * 784 + 196 + q] +
             b2 * lw[j * 784 + 392 + q] + b3 * lw[j * 784 + 588 + q];
      ws[WS_CST + u] = s;
    } else if (u == 40) {
      ws[WS_A] = (cb[0] + cb[1] + cb[2] + cb[3]) * 0.25f;
    }
  }
}

#define BAR()                                            \
  asm volatile("s_waitcnt lgkmcnt(0)" ::: "memory");     \
  __builtin_amdgcn_s_barrier();                          \
  asm volatile("" ::: "memory");

// Broadcast float I of the wave's G row (held as per-lane float4 over lanes
// 0..41) into an SGPR: compile-time component select + v_readlane.
template <int I>
__device__ __forceinline__ float rl(const float4& v) {
  constexpr int c = I & 3;
  const float f = (c == 0) ? v.x : (c == 1) ? v.y : (c == 2) ? v.z : v.w;
  return __int_as_float(__builtin_amdgcn_readlane(__float_as_int(f), I >> 2));
}

// One pixel-pair P (cols 2P,2P+1; shared d-class): 12 readlane + 12 fmac.
#define PAIRR(P, PAR, GB)                                                     \
  {                                                                           \
    __builtin_amdgcn_sched_barrier(0);                                        \
    constexpr int DD = (2 * (PAR) + ((P)&3)) & 3;                             \
    const float xA = ((P)&1) ? tr[(P) >> 1].z : tr[(P) >> 1].x;               \
    const float xB = ((P)&1) ? tr[(P) >> 1].w : tr[(P) >> 1].y;               \
    acc[DD][0] += xA * rl<12 * (P) + 0>(GB);                                  \
    acc[DD][1] += xA * rl<12 * (P) + 1>(GB);                                  \
    acc[DD][2] += xA * rl<12 * (P) + 2>(GB);                                  \
    acc[DD][3] += xA * rl<12 * (P) + 3>(GB);                                  \
    acc[DD][4] += xA * rl<12 * (P) + 4>(GB);                                  \
    acc[DD][5] += xA * rl<12 * (P) + 5>(GB);                                  \
    acc[DD][0] += xB * rl<12 * (P) + 6>(GB);                                  \
    acc[DD][1] += xB * rl<12 * (P) + 7>(GB);                                  \
    acc[DD][2] += xB * rl<12 * (P) + 8>(GB);                                  \
    acc[DD][3] += xB * rl<12 * (P) + 9>(GB);                                  \
    acc[DD][4] += xB * rl<12 * (P) + 10>(GB);                                 \
    acc[DD][5] += xB * rl<12 * (P) + 11>(GB);                                 \
  }

// Computing part of a step: prefetch next computing row's G slice (one
// coalesced per-lane float4, consumed 2 steps later), read own sample's row
// from the plane, run 14 pair blocks.
#define COMPUTE(S, GCUR, GNXT)                                                \
  {                                                                           \
    const int rnx = (r_ + 2 < 28) ? r_ + 2 : 27;                              \
    GNXT = *reinterpret_cast<const float4*>(gsl + rnx * 168);                 \
    const float* rp = smem + ((S)&3) * 2304 + lane36;                         \
    float4 tr[7];                                                             \
    _Pragma("unroll") for (int mm = 0; mm < 7; ++mm)                          \
      tr[mm] = *reinterpret_cast<const float4*>(rp + mm * 4);                 \
    PAIRR(0, ((S) >> 1) & 1, GCUR)  PAIRR(1, ((S) >> 1) & 1, GCUR)            \
    PAIRR(2, ((S) >> 1) & 1, GCUR)  PAIRR(3, ((S) >> 1) & 1, GCUR)            \
    PAIRR(4, ((S) >> 1) & 1, GCUR)  PAIRR(5, ((S) >> 1) & 1, GCUR)            \
    PAIRR(6, ((S) >> 1) & 1, GCUR)  PAIRR(7, ((S) >> 1) & 1, GCUR)            \
    PAIRR(8, ((S) >> 1) & 1, GCUR)  PAIRR(9, ((S) >> 1) & 1, GCUR)            \
    PAIRR(10, ((S) >> 1) & 1, GCUR) PAIRR(11, ((S) >> 1) & 1, GCUR)           \
    PAIRR(12, ((S) >> 1) & 1, GCUR) PAIRR(13, ((S) >> 1) & 1, GCUR)           \
  }

// Step S (0..3): row r_ = rb+S (plane r_%4 == S). Stage row r_+3 into plane
// (S+3)&3 (last read at step S-1, protected by that step's barrier), reload
// its R-slot with row r_+7. Matching-parity waves compute. lgkmcnt(0)-only
// drain + raw barrier keeps global prefetch (vmcnt) in flight.
#define STEP(S, GCUR, GNXT)                                                   \
  {                                                                           \
    const int r_ = rb + (S);                                                  \
    if (r_ + 3 < 28) {                                                        \
      float* wp = smem + (((S) + 3) & 3) * 2304;                              \
      *reinterpret_cast<float4*>(wp + wadr1) = R1[((S) + 3) & 3];             \
      if (has2) *reinterpret_cast<float4*>(wp + wadr2) = R2[((S) + 3) & 3];   \
      if (r_ + 7 < 28) {                                                      \
        R1[((S) + 3) & 3] =                                                   \
            *reinterpret_cast<const float4*>(xg1 + (r_ + 7) * 28);            \
        if (has2)                                                             \
          R2[((S) + 3) & 3] =                                                 \
              *reinterpret_cast<const float4*>(xg2 + (r_ + 7) * 28);          \
      }                                                                       \
    }                                                                         \
    if (rh == ((S)&1)) { COMPUTE(S, GCUR, GNXT) }                             \
    BAR()                                                                     \
  }

__global__ __launch_bounds__(256)
__attribute__((amdgpu_waves_per_eu(2, 2))) void qsac_main(
    const float* __restrict__ x, const float* __restrict__ ws,
    const float* __restrict__ lin_b, float* __restrict__ out) {
  __shared__ float smem[4 * 2304];  // 36.9 KB: 4 x-planes [64][36]

  const int tid = threadIdx.x;
  const int lane = tid & 63;
  const int wid = __builtin_amdgcn_readfirstlane(tid >> 6);
  const int ch = wid >> 1, rh = wid & 1;
  const int sbase = blockIdx.x * 64;
  const int lane36 = lane * 36;
  // Per-lane G slice pointer: lane l<42 covers floats [4l,4l+4) of each
  // 168-float row of this wave's ch slice (lanes >=42 clamp to 0, unused).
  const float* gsl = ws + ch * 4704 + ((lane < 42) ? lane * 4 : 0);

  // x staging: chunk c -> sample s=c/7, 16B-piece m=c%7. c1 = tid (all),
  // c2 = tid+256 (tid<192; wave-uniform since 192 = 3*64). 448 chunks/row.
  const int s1 = tid / 7, m1 = tid - s1 * 7;
  const bool has2 = tid < 192;
  const int c2 = tid + 256;
  const int s2 = c2 / 7, m2 = c2 - s2 * 7;
  const float* xg1 = x + (size_t)(sbase + s1) * 784 + m1 * 4;
  const float* xg2 = x + (size_t)(sbase + (has2 ? s2 : 0)) * 784 + m2 * 4;
  const int wadr1 = s1 * 36 + m1 * 4;
  const int wadr2 = s2 * 36 + m2 * 4;

  // G double-buffer: Gb0 <- first computing row (row rh).
  float4 Gb0, Gb1;
  Gb0 = *reinterpret_cast<const float4*>(gsl + rh * 168);

  // Prologue: rows 0-2 -> planes 0-2; rows 3-6 -> R*[3],R*[0],R*[1],R*[2].
  float4 R1[4], R2[4];
  float4 a0 = *reinterpret_cast<const float4*>(xg1);
  float4 a1 = *reinterpret_cast<const float4*>(xg1 + 28);
  float4 a2 = *reinterpret_cast<const float4*>(xg1 + 56);
  float4 b0, b1, b2;
  if (has2) {
    b0 = *reinterpret_cast<const float4*>(xg2);
    b1 = *reinterpret_cast<const float4*>(xg2 + 28);
    b2 = *reinterpret_cast<const float4*>(xg2 + 56);
  }
  R1[3] = *reinterpret_cast<const float4*>(xg1 + 3 * 28);
  R1[0] = *reinterpret_cast<const float4*>(xg1 + 4 * 28);
  R1[1] = *reinterpret_cast<const float4*>(xg1 + 5 * 28);
  R1[2] = *reinterpret_cast<const float4*>(xg1 + 6 * 28);
  if (has2) {
    R2[3] = *reinterpret_cast<const float4*>(xg2 + 3 * 28);
    R2[0] = *reinterpret_cast<const float4*>(xg2 + 4 * 28);
    R2[1] = *reinterpret_cast<const float4*>(xg2 + 5 * 28);
    R2[2] = *reinterpret_cast<const float4*>(xg2 + 6 * 28);
  }
  *reinterpret_cast<float4*>(smem + 0 * 2304 + wadr1) = a0;
  *reinterpret_cast<float4*>(smem + 1 * 2304 + wadr1) = a1;
  *reinterpret_cast<float4*>(smem + 2 * 2304 + wadr1) = a2;
  if (has2) {
    *reinterpret_cast<float4*>(smem + 0 * 2304 + wadr2) = b0;
    *reinterpret_cast<float4*>(smem + 1 * 2304 + wadr2) = b1;
    *reinterpret_cast<float4*>(smem + 2 * 2304 + wadr2) = b2;
  }
  BAR()

  float acc[4][6];
#pragma unroll
  for (int d = 0; d < 4; ++d)
#pragma unroll
    for (int q = 0; q < 6; ++q) acc[d][q] = 0.f;

  // Computing rows per wave: r = rh, rh+2, ..., rh+26. Gbuf ping-pong:
  // even computing-step uses Gb0/prefetches Gb1, odd uses Gb1/prefetches Gb0.
#pragma unroll 1
  for (int it = 0; it < 7; ++it) {
    const int rb = it * 4;
    STEP(0, Gb0, Gb1) STEP(1, Gb0, Gb1) STEP(2, Gb1, Gb0) STEP(3, Gb1, Gb0)
  }

  // ---- epilogue (planes dead; overlay Red [0,3072) / Mld [3072,3328) /
  // L [3328,4096)) ----
  if (rh == 1) {
    float* rd = smem + ch * 1536 + lane * 24;
#pragma unroll
    for (int d = 0; d < 4; ++d)
#pragma unroll
      for (int q = 0; q < 6; ++q) rd[d * 6 + q] = acc[d][q];
  }
  __syncthreads();
  if (rh == 0) {
    const float* rd = smem + ch * 1536 + lane * 24;
#pragma unroll
    for (int d = 0; d < 4; ++d)
#pragma unroll
      for (int q = 0; q < 6; ++q) acc[d][q] += rd[d * 6 + q];
  }
  if (wid == 2) {  // ch1, rh0: full mean sums in slot 5 after reduction
    const float a = ws[WS_A];
#pragma unroll
    for (int d = 0; d < 4; ++d) smem[3072 + lane * 4 + d] = a + acc[d][5];
  }
  __syncthreads();
  if (rh == 0) {
    float M[4];
#pragma unroll
    for (int d = 0; d < 4; ++d) M[d] = smem[3072 + lane * 4 + d];
#pragma unroll
    for (int q = 0; q < 5; ++q) {
      const int j = ch * 5 + q;
      float v = lin_b[j];
#pragma unroll
      for (int d = 0; d < 4; ++d)
        v += M[d] * (ws[WS_CST + d * 10 + j] + acc[d][q]);
      smem[3328 + lane * 12 + j] = v;
    }
  }
  __syncthreads();
  if (wid == 0) {
    float logits[10];
#pragma unroll
    for (int j = 0; j < 10; ++j) logits[j] = smem[3328 + lane * 12 + j];
    float mx = logits[0];
#pragma unroll
    for (int j = 1; j < 10; ++j) mx = fmaxf(mx, logits[j]);
    float se = 0.f;
#pragma unroll
    for (int j = 0; j < 10; ++j) se += __expf(logits[j] - mx);
    const float lse = mx + __logf(se);
    float* op = out + (size_t)(sbase + lane) * 10;
#pragma unroll
    for (int j = 0; j < 10; ++j) op[j] = logits[j] - lse;
  }
}

extern "C" void kernel_launch(void* const* d_in, const int* in_sizes, int n_in,
                              void* d_out, int out_size, void* d_ws, size_t ws_size,
                              hipStream_t stream) {
  (void)n_in; (void)ws_size; (void)out_size;
  const float* x = (const float*)d_in[0];
  const float* conv_w = (const float*)d_in[1];
  const float* conv_b = (const float*)d_in[2];
  // d_in[3]/d_in[4] (rotation/entangle) are dead: softmax over length-1 == 1.
  const float* lin_w = (const float*)d_in[5];
  const float* lin_b = (const float*)d_in[6];
  float* out = (float*)d_out;
  float* ws = (float*)d_ws;

  hipLaunchKernelGGL(qsac_prep, dim3(8), dim3(98), 0, stream,
                     conv_w, conv_b, lin_w, ws);

  const int B = in_sizes[0] / 784;  // 32768
  const int nblk = B / 64;          // 512 blocks x 256 threads
  hipLaunchKernelGGL(qsac_main, dim3(nblk), dim3(256), 0, stream,
                     x, ws, lin_b, out);
}